// Round 5
// baseline (277.963 us; speedup 1.0000x reference)
//
#include <hip/hip_runtime.h>
#include <math.h>

typedef __attribute__((ext_vector_type(8))) short short8;
typedef __attribute__((ext_vector_type(4))) float f32x4;

namespace {
constexpr int BATCH = 4096;
constexpr int SEQT  = 256;
constexpr int INSZ  = 24;
constexpr int H     = 40;
constexpr int NOUT  = 24;
constexpr int R     = 8;     // batch rows per block, grid = 512 (2 blocks/CU -> 2 waves/SIMD)
constexpr int NT    = 256;   // 4 waves: 0-2 gate (u-ranges), 3 FC + x staging

__device__ __forceinline__ unsigned short f2bf(float f) {
  unsigned int u = __float_as_uint(f);
  return (unsigned short)((u + 0x7FFFu + ((u >> 16) & 1u)) >> 16);  // RNE
}
__device__ __forceinline__ float4 ld4(const float* p) {
  return *reinterpret_cast<const float4*>(p);
}
__device__ __forceinline__ float sigm(float v) { return 1.0f / (1.0f + __expf(-v)); }
__device__ __forceinline__ float tanh_fast(float v) {
  return 2.0f / (1.0f + __expf(-2.0f * v)) - 1.0f;
}
}  // namespace

// A-operand layout (bf16): Abuf row = batch row (8 valid, 8 pad), k = [x(0..23) | h(24..63)],
// swizzle idx^=(row&7)<<3. Gate wave w (0..2): zone tiles r,z,nx,nh for u = w*16+lm (u<40).
// Lane (lq,lm) owns D rows lq*4+0..3 of unit u for ALL 4 zones -> in-lane gate math,
// fp32 h state in registers, one barrier per step. Padded rows compute garbage that is
// row-contained and never stored.
__global__ __launch_bounds__(NT) void gru_mfma4(
    const float* __restrict__ x, const float* __restrict__ Wih,
    const float* __restrict__ Whh, const float* __restrict__ bih,
    const float* __restrict__ bhh, const float* __restrict__ Wfc,
    const float* __restrict__ bfc, float* __restrict__ out,
    float* __restrict__ hid) {
  __shared__ __align__(16) unsigned short Abuf[2 * 1024];

  const int tid = threadIdx.x;
  const int l   = tid & 63;
  const int w   = tid >> 6;
  const int lm  = l & 15;
  const int lq  = l >> 4;
  const int gb0 = blockIdx.x * R;

  reinterpret_cast<uint4*>(Abuf)[tid] = make_uint4(0, 0, 0, 0);  // zero both buffers

  const int aBase0 = ((lm * 64 + lq * 8)      ^ ((lm & 7) << 3));
  const int aBase1 = ((lm * 64 + lq * 8 + 32) ^ ((lm & 7) << 3));

  // ---------------- gate role (waves 0..2) ----------------
  short8 B[4][2];
  float bias[4] = {0, 0, 0, 0};
  float hold[4] = {0, 0, 0, 0};
  int aw[4] = {0, 0, 0, 0};
  int u = 0;
  bool gvalid = false;
  if (w < 3) {
    u = w * 16 + lm;
    gvalid = (u < H);
#pragma unroll
    for (int z = 0; z < 4; ++z) {
#pragma unroll
      for (int kt = 0; kt < 2; ++kt) {
        short8 b;
#pragma unroll
        for (int j = 0; j < 8; ++j) {
          const int k = kt * 32 + lq * 8 + j;
          float v = 0.0f;
          if (gvalid) {
            if (z == 0)      v = (k < 24) ? Wih[u * 24 + k]          : Whh[u * 40 + (k - 24)];
            else if (z == 1) v = (k < 24) ? Wih[(40 + u) * 24 + k]   : Whh[(40 + u) * 40 + (k - 24)];
            else if (z == 2) v = (k < 24) ? Wih[(80 + u) * 24 + k]   : 0.0f;
            else             v = (k < 24) ? 0.0f                     : Whh[(80 + u) * 40 + (k - 24)];
          }
          b[j] = (short)f2bf(v);
        }
        B[z][kt] = b;
      }
    }
    if (gvalid) {
      bias[0] = bih[u] + bhh[u];
      bias[1] = bih[40 + u] + bhh[40 + u];
      bias[2] = bih[80 + u];           // n input bias
      bias[3] = bhh[80 + u];           // n hidden bias (scaled by r)
    }
#pragma unroll
    for (int i = 0; i < 4; ++i)
      aw[i] = (((lq * 4 + i) * 64 + 24 + u) ^ (((lq * 4 + i) & 7) << 3));
  }

  // ---------------- FC + x role (wave 3) ----------------
  short8 F[2][2];
  float biasF[2] = {0, 0};
  float* orow[4] = {nullptr, nullptr, nullptr, nullptr};
  const float* xp0 = nullptr;
  int xw0 = 0;
  bool xv = false;
  float4 xA0 = make_float4(0, 0, 0, 0), xB0 = make_float4(0, 0, 0, 0);
  if (w == 3) {
#pragma unroll
    for (int f = 0; f < 2; ++f) {
      const int o = f * 16 + lm;
#pragma unroll
      for (int kt = 0; kt < 2; ++kt) {
        short8 b;
#pragma unroll
        for (int j = 0; j < 8; ++j) {
          const int k = kt * 32 + lq * 8 + j;
          const float v = (o < NOUT && k >= 24) ? Wfc[o * H + (k - 24)] : 0.0f;
          b[j] = (short)f2bf(v);
        }
        F[f][kt] = b;
      }
      biasF[f] = (o < NOUT) ? bfc[o] : 0.0f;
    }
#pragma unroll
    for (int i = 0; i < 4; ++i)
      orow[i] = out + ((size_t)(gb0 + lq * 4 + i) * SEQT) * NOUT;  // valid only lq<2

    // x staging: 48 float4 chunks (8 rows x 6), one per lane l<48
    xv = (l < 48);
    const int xr0 = l / 6, xc0 = (l - xr0 * 6) * 4;
    if (xv) xp0 = x + ((size_t)(gb0 + xr0) * SEQT) * INSZ + xc0;
    xw0 = ((xr0 * 64 + xc0) ^ ((xr0 & 7) << 3));
  }

  __syncthreads();  // Abuf zeroed

  if (w == 3 && xv) {  // stage x(0) into buf0; prefetch x(1), x(2) into regs
    const float4 v0 = ld4(xp0);
    *reinterpret_cast<uint2*>(&Abuf[xw0]) = make_uint2(
        (unsigned)f2bf(v0.x) | ((unsigned)f2bf(v0.y) << 16),
        (unsigned)f2bf(v0.z) | ((unsigned)f2bf(v0.w) << 16));
    xA0 = ld4(xp0 + 1 * INSZ);
    xB0 = ld4(xp0 + 2 * INSZ);
  }
  __syncthreads();  // x(0) staged

#define GATE_STEP(BO, NBO)                                                      \
  if (w < 3) {                                                                  \
    const short8 A0 = *reinterpret_cast<const short8*>(&Abuf[(BO) + aBase0]);   \
    const short8 A1 = *reinterpret_cast<const short8*>(&Abuf[(BO) + aBase1]);   \
    f32x4 ar = {bias[0], bias[0], bias[0], bias[0]};                            \
    f32x4 az = {bias[1], bias[1], bias[1], bias[1]};                            \
    f32x4 ax = {bias[2], bias[2], bias[2], bias[2]};                            \
    f32x4 ah = {bias[3], bias[3], bias[3], bias[3]};                            \
    ar = __builtin_amdgcn_mfma_f32_16x16x32_bf16(A0, B[0][0], ar, 0, 0, 0);     \
    az = __builtin_amdgcn_mfma_f32_16x16x32_bf16(A0, B[1][0], az, 0, 0, 0);     \
    ax = __builtin_amdgcn_mfma_f32_16x16x32_bf16(A0, B[2][0], ax, 0, 0, 0);     \
    ah = __builtin_amdgcn_mfma_f32_16x16x32_bf16(A0, B[3][0], ah, 0, 0, 0);     \
    ar = __builtin_amdgcn_mfma_f32_16x16x32_bf16(A1, B[0][1], ar, 0, 0, 0);     \
    az = __builtin_amdgcn_mfma_f32_16x16x32_bf16(A1, B[1][1], az, 0, 0, 0);     \
    ax = __builtin_amdgcn_mfma_f32_16x16x32_bf16(A1, B[2][1], ax, 0, 0, 0);     \
    ah = __builtin_amdgcn_mfma_f32_16x16x32_bf16(A1, B[3][1], ah, 0, 0, 0);     \
    _Pragma("unroll")                                                           \
    for (int i = 0; i < 4; ++i) {                                               \
      const float rr = sigm(ar[i]);                                             \
      const float zz = sigm(az[i]);                                             \
      const float nn = tanh_fast(ax[i] + rr * ah[i]);                           \
      const float h  = (1.0f - zz) * nn + zz * hold[i];                         \
      hold[i] = h;                                                              \
      if (gvalid) Abuf[(NBO) + aw[i]] = f2bf(h);                                \
    }                                                                           \
  }

#define XSTAGE(T, NBO, XS)                                                      \
  if (w == 3 && xv) {                                                           \
    *reinterpret_cast<uint2*>(&Abuf[(NBO) + xw0]) = make_uint2(                 \
        (unsigned)f2bf(XS.x) | ((unsigned)f2bf(XS.y) << 16),                    \
        (unsigned)f2bf(XS.z) | ((unsigned)f2bf(XS.w) << 16));                   \
    if ((T) + 3 < SEQT) XS = ld4(xp0 + (size_t)((T) + 3) * INSZ);               \
  }

#define FC_STEP(T, NBO)                                                         \
  if (w == 3) {                                                                 \
    const short8 hA0 = *reinterpret_cast<const short8*>(&Abuf[(NBO) + aBase0]); \
    const short8 hA1 = *reinterpret_cast<const short8*>(&Abuf[(NBO) + aBase1]); \
    f32x4 f0 = {biasF[0], biasF[0], biasF[0], biasF[0]};                        \
    f32x4 f1 = {biasF[1], biasF[1], biasF[1], biasF[1]};                        \
    f0 = __builtin_amdgcn_mfma_f32_16x16x32_bf16(hA0, F[0][0], f0, 0, 0, 0);    \
    f1 = __builtin_amdgcn_mfma_f32_16x16x32_bf16(hA0, F[1][0], f1, 0, 0, 0);    \
    f0 = __builtin_amdgcn_mfma_f32_16x16x32_bf16(hA1, F[0][1], f0, 0, 0, 0);    \
    f1 = __builtin_amdgcn_mfma_f32_16x16x32_bf16(hA1, F[1][1], f1, 0, 0, 0);    \
    if (lq < 2) {                                                               \
      _Pragma("unroll")                                                         \
      for (int i = 0; i < 4; ++i) {                                             \
        orow[i][(size_t)(T) * NOUT + lm] = sigm(f0[i]);                         \
        if (lm < 8) orow[i][(size_t)(T) * NOUT + 16 + lm] = sigm(f1[i]);        \
      }                                                                         \
    }                                                                           \
  }

  for (int tt = 0; tt < SEQT; tt += 2) {
    // step t = tt (even): cur buf 0, next buf 1
    GATE_STEP(0, 1024)
    XSTAGE(tt, 1024, xA0)
    __syncthreads();
    FC_STEP(tt, 1024)
    // step t = tt+1 (odd): cur buf 1, next buf 0
    GATE_STEP(1024, 0)
    XSTAGE(tt + 1, 0, xB0)
    __syncthreads();
    FC_STEP(tt + 1, 0)
  }

  // final hidden state from registers (rows 0..7 only)
  if (w < 3 && gvalid && lq < 2) {
#pragma unroll
    for (int i = 0; i < 4; ++i)
      hid[(size_t)(gb0 + lq * 4 + i) * H + u] = hold[i];
  }
}

extern "C" void kernel_launch(void* const* d_in, const int* in_sizes, int n_in,
                              void* d_out, int out_size, void* d_ws, size_t ws_size,
                              hipStream_t stream) {
  const float* x   = (const float*)d_in[0];
  const float* Wih = (const float*)d_in[1];
  const float* Whh = (const float*)d_in[2];
  const float* bih = (const float*)d_in[3];
  const float* bhh = (const float*)d_in[4];
  const float* Wfc = (const float*)d_in[5];
  const float* bfc = (const float*)d_in[6];
  float* out = (float*)d_out;
  float* hid = out + (size_t)BATCH * SEQT * NOUT;

  dim3 grid(BATCH / R);
  dim3 block(NT);
  hipLaunchKernelGGL(gru_mfma4, grid, block, 0, stream,
                     x, Wih, Whh, bih, bhh, Wfc, bfc, out, hid);
}

// Round 6
// 183.576 us; speedup vs baseline: 1.5142x; 1.5142x over previous
//
#include <hip/hip_runtime.h>
#include <math.h>

typedef __attribute__((ext_vector_type(8))) short short8;
typedef __attribute__((ext_vector_type(4))) float f32x4;

namespace {
constexpr int BATCH = 4096;
constexpr int SEQT  = 256;
constexpr int INSZ  = 24;
constexpr int H     = 40;
constexpr int NOUT  = 24;
constexpr int R     = 16;    // batch rows per block, grid = 256 (1 block/CU)
constexpr int NT    = 256;   // 4 waves: 0-2 gate (u-ranges), 3 FC + x staging

__device__ __forceinline__ unsigned short f2bf(float f) {
  unsigned int u = __float_as_uint(f);
  return (unsigned short)((u + 0x7FFFu + ((u >> 16) & 1u)) >> 16);  // RNE
}
__device__ __forceinline__ float4 ld4(const float* p) {
  return *reinterpret_cast<const float4*>(p);
}
__device__ __forceinline__ float sigm(float v) { return 1.0f / (1.0f + __expf(-v)); }
__device__ __forceinline__ float tanh_fast(float v) {
  return 2.0f / (1.0f + __expf(-2.0f * v)) - 1.0f;
}
}  // namespace

// Raw barrier: only drain LDS ops (h/x ds_writes must be visible to readers).
// Global prefetch loads + output stores stay IN FLIGHT across the barrier —
// __syncthreads would emit s_waitcnt vmcnt(0) and expose ~900cy HBM latency
// every step (this was R4's hidden 4x).
#define BAR()                                              \
  asm volatile("s_waitcnt lgkmcnt(0)" ::: "memory");       \
  __builtin_amdgcn_s_barrier();                            \
  __builtin_amdgcn_sched_barrier(0);

// A-operand layout (bf16): Abuf row = batch row (16), k = [x(0..23) | h(24..63)],
// swizzle idx^=(row&7)<<3. Gate wave w (0..2): zone tiles r,z,nx,nh for u = w*16+lm
// (u<40). Lane (lq,lm) owns D rows lq*4+0..3 of unit u for ALL 4 zones -> in-lane
// gate math, fp32 h state in registers, one raw barrier per step.
__global__ __launch_bounds__(NT) void gru_mfma4(
    const float* __restrict__ x, const float* __restrict__ Wih,
    const float* __restrict__ Whh, const float* __restrict__ bih,
    const float* __restrict__ bhh, const float* __restrict__ Wfc,
    const float* __restrict__ bfc, float* __restrict__ out,
    float* __restrict__ hid) {
  __shared__ __align__(16) unsigned short Abuf[2 * 1024];

  const int tid = threadIdx.x;
  const int l   = tid & 63;
  const int w   = tid >> 6;
  const int lm  = l & 15;
  const int lq  = l >> 4;
  const int gb0 = blockIdx.x * R;

  reinterpret_cast<uint4*>(Abuf)[tid] = make_uint4(0, 0, 0, 0);  // zero both buffers

  const int aBase0 = ((lm * 64 + lq * 8)      ^ ((lm & 7) << 3));
  const int aBase1 = ((lm * 64 + lq * 8 + 32) ^ ((lm & 7) << 3));

  // ---------------- gate role (waves 0..2) ----------------
  short8 B[4][2];
  float bias[4] = {0, 0, 0, 0};
  float hold[4] = {0, 0, 0, 0};
  int aw[4] = {0, 0, 0, 0};
  int u = 0;
  bool gvalid = false;
  if (w < 3) {
    u = w * 16 + lm;
    gvalid = (u < H);
#pragma unroll
    for (int z = 0; z < 4; ++z) {
#pragma unroll
      for (int kt = 0; kt < 2; ++kt) {
        short8 b;
#pragma unroll
        for (int j = 0; j < 8; ++j) {
          const int k = kt * 32 + lq * 8 + j;
          float v = 0.0f;
          if (gvalid) {
            if (z == 0)      v = (k < 24) ? Wih[u * 24 + k]          : Whh[u * 40 + (k - 24)];
            else if (z == 1) v = (k < 24) ? Wih[(40 + u) * 24 + k]   : Whh[(40 + u) * 40 + (k - 24)];
            else if (z == 2) v = (k < 24) ? Wih[(80 + u) * 24 + k]   : 0.0f;
            else             v = (k < 24) ? 0.0f                     : Whh[(80 + u) * 40 + (k - 24)];
          }
          b[j] = (short)f2bf(v);
        }
        B[z][kt] = b;
      }
    }
    if (gvalid) {
      bias[0] = bih[u] + bhh[u];
      bias[1] = bih[40 + u] + bhh[40 + u];
      bias[2] = bih[80 + u];           // n input bias
      bias[3] = bhh[80 + u];           // n hidden bias (scaled by r)
    }
#pragma unroll
    for (int i = 0; i < 4; ++i)
      aw[i] = (((lq * 4 + i) * 64 + 24 + u) ^ (((lq * 4 + i) & 7) << 3));
  }

  // ---------------- FC + x role (wave 3) ----------------
  short8 F[2][2];
  float biasF[2] = {0, 0};
  float* orow[4] = {nullptr, nullptr, nullptr, nullptr};
  const float* xp0 = nullptr;
  const float* xp1 = nullptr;
  int xw0 = 0, xw1 = 0;
  bool x1v = false;
  float4 xA0 = make_float4(0,0,0,0), xA1 = make_float4(0,0,0,0);
  float4 xB0 = make_float4(0,0,0,0), xB1 = make_float4(0,0,0,0);
  if (w == 3) {
#pragma unroll
    for (int f = 0; f < 2; ++f) {
      const int o = f * 16 + lm;
#pragma unroll
      for (int kt = 0; kt < 2; ++kt) {
        short8 b;
#pragma unroll
        for (int j = 0; j < 8; ++j) {
          const int k = kt * 32 + lq * 8 + j;
          const float v = (o < NOUT && k >= 24) ? Wfc[o * H + (k - 24)] : 0.0f;
          b[j] = (short)f2bf(v);
        }
        F[f][kt] = b;
      }
      biasF[f] = (o < NOUT) ? bfc[o] : 0.0f;
    }
#pragma unroll
    for (int i = 0; i < 4; ++i)
      orow[i] = out + ((size_t)(gb0 + lq * 4 + i) * SEQT) * NOUT;

    // x staging: 96 float4 chunks (16 rows x 6), items l and 64+l (l<32)
    const int i0 = l, i1 = 64 + l;
    const int xr0 = i0 / 6, xc0 = (i0 - xr0 * 6) * 4;
    const int xr1 = i1 / 6, xc1 = (i1 - xr1 * 6) * 4;
    x1v = (l < 32);
    xp0 = x + ((size_t)(gb0 + xr0) * SEQT) * INSZ + xc0;
    if (x1v) xp1 = x + ((size_t)(gb0 + xr1) * SEQT) * INSZ + xc1;
    xw0 = ((xr0 * 64 + xc0) ^ ((xr0 & 7) << 3));
    xw1 = ((xr1 * 64 + xc1) ^ ((xr1 & 7) << 3));
  }

  __syncthreads();  // Abuf zeroed

  if (w == 3) {  // stage x(0) into buf0; prefetch x(1), x(2) into regs
    const float4 v0 = ld4(xp0);
    *reinterpret_cast<uint2*>(&Abuf[xw0]) = make_uint2(
        (unsigned)f2bf(v0.x) | ((unsigned)f2bf(v0.y) << 16),
        (unsigned)f2bf(v0.z) | ((unsigned)f2bf(v0.w) << 16));
    if (x1v) {
      const float4 v1 = ld4(xp1);
      *reinterpret_cast<uint2*>(&Abuf[xw1]) = make_uint2(
          (unsigned)f2bf(v1.x) | ((unsigned)f2bf(v1.y) << 16),
          (unsigned)f2bf(v1.z) | ((unsigned)f2bf(v1.w) << 16));
    }
    xA0 = ld4(xp0 + 1 * INSZ);
    xB0 = ld4(xp0 + 2 * INSZ);
    if (x1v) { xA1 = ld4(xp1 + 1 * INSZ); xB1 = ld4(xp1 + 2 * INSZ); }
  }
  __syncthreads();  // x(0) staged

#define GATE_STEP(BO, NBO)                                                      \
  if (w < 3) {                                                                  \
    const short8 A0 = *reinterpret_cast<const short8*>(&Abuf[(BO) + aBase0]);   \
    const short8 A1 = *reinterpret_cast<const short8*>(&Abuf[(BO) + aBase1]);   \
    f32x4 ar = {bias[0], bias[0], bias[0], bias[0]};                            \
    f32x4 az = {bias[1], bias[1], bias[1], bias[1]};                            \
    f32x4 ax = {bias[2], bias[2], bias[2], bias[2]};                            \
    f32x4 ah = {bias[3], bias[3], bias[3], bias[3]};                            \
    ar = __builtin_amdgcn_mfma_f32_16x16x32_bf16(A0, B[0][0], ar, 0, 0, 0);     \
    az = __builtin_amdgcn_mfma_f32_16x16x32_bf16(A0, B[1][0], az, 0, 0, 0);     \
    ax = __builtin_amdgcn_mfma_f32_16x16x32_bf16(A0, B[2][0], ax, 0, 0, 0);     \
    ah = __builtin_amdgcn_mfma_f32_16x16x32_bf16(A0, B[3][0], ah, 0, 0, 0);     \
    ar = __builtin_amdgcn_mfma_f32_16x16x32_bf16(A1, B[0][1], ar, 0, 0, 0);     \
    az = __builtin_amdgcn_mfma_f32_16x16x32_bf16(A1, B[1][1], az, 0, 0, 0);     \
    ax = __builtin_amdgcn_mfma_f32_16x16x32_bf16(A1, B[2][1], ax, 0, 0, 0);     \
    ah = __builtin_amdgcn_mfma_f32_16x16x32_bf16(A1, B[3][1], ah, 0, 0, 0);     \
    _Pragma("unroll")                                                           \
    for (int i = 0; i < 4; ++i) {                                               \
      const float rr = sigm(ar[i]);                                             \
      const float zz = sigm(az[i]);                                             \
      const float nn = tanh_fast(ax[i] + rr * ah[i]);                           \
      const float h  = (1.0f - zz) * nn + zz * hold[i];                         \
      hold[i] = h;                                                              \
      if (gvalid) Abuf[(NBO) + aw[i]] = f2bf(h);                                \
    }                                                                           \
  }

#define XSTAGE(T, NBO, XS0, XS1)                                                \
  if (w == 3) {                                                                 \
    *reinterpret_cast<uint2*>(&Abuf[(NBO) + xw0]) = make_uint2(                 \
        (unsigned)f2bf(XS0.x) | ((unsigned)f2bf(XS0.y) << 16),                  \
        (unsigned)f2bf(XS0.z) | ((unsigned)f2bf(XS0.w) << 16));                 \
    if (x1v)                                                                    \
      *reinterpret_cast<uint2*>(&Abuf[(NBO) + xw1]) = make_uint2(               \
          (unsigned)f2bf(XS1.x) | ((unsigned)f2bf(XS1.y) << 16),                \
          (unsigned)f2bf(XS1.z) | ((unsigned)f2bf(XS1.w) << 16));               \
    if ((T) + 3 < SEQT) {                                                       \
      XS0 = ld4(xp0 + (size_t)((T) + 3) * INSZ);                                \
      if (x1v) XS1 = ld4(xp1 + (size_t)((T) + 3) * INSZ);                       \
    }                                                                           \
  }

#define FC_STEP(T, NBO)                                                         \
  if (w == 3) {                                                                 \
    const short8 hA0 = *reinterpret_cast<const short8*>(&Abuf[(NBO) + aBase0]); \
    const short8 hA1 = *reinterpret_cast<const short8*>(&Abuf[(NBO) + aBase1]); \
    f32x4 f0 = {biasF[0], biasF[0], biasF[0], biasF[0]};                        \
    f32x4 f1 = {biasF[1], biasF[1], biasF[1], biasF[1]};                        \
    f0 = __builtin_amdgcn_mfma_f32_16x16x32_bf16(hA0, F[0][0], f0, 0, 0, 0);    \
    f1 = __builtin_amdgcn_mfma_f32_16x16x32_bf16(hA0, F[1][0], f1, 0, 0, 0);    \
    f0 = __builtin_amdgcn_mfma_f32_16x16x32_bf16(hA1, F[0][1], f0, 0, 0, 0);    \
    f1 = __builtin_amdgcn_mfma_f32_16x16x32_bf16(hA1, F[1][1], f1, 0, 0, 0);    \
    _Pragma("unroll")                                                           \
    for (int i = 0; i < 4; ++i) {                                               \
      orow[i][(size_t)(T) * NOUT + lm] = sigm(f0[i]);                           \
      if (lm < 8) orow[i][(size_t)(T) * NOUT + 16 + lm] = sigm(f1[i]);          \
    }                                                                           \
  }

  for (int tt = 0; tt < SEQT; tt += 2) {
    // step t = tt (even): cur buf 0, next buf 1
    GATE_STEP(0, 1024)
    XSTAGE(tt, 1024, xA0, xA1)
    BAR()
    FC_STEP(tt, 1024)
    // step t = tt+1 (odd): cur buf 1, next buf 0
    GATE_STEP(1024, 0)
    XSTAGE(tt + 1, 0, xB0, xB1)
    BAR()
    FC_STEP(tt + 1, 0)
  }

  // final hidden state from registers
  if (w < 3 && gvalid) {
#pragma unroll
    for (int i = 0; i < 4; ++i)
      hid[(size_t)(gb0 + lq * 4 + i) * H + u] = hold[i];
  }
}

extern "C" void kernel_launch(void* const* d_in, const int* in_sizes, int n_in,
                              void* d_out, int out_size, void* d_ws, size_t ws_size,
                              hipStream_t stream) {
  const float* x   = (const float*)d_in[0];
  const float* Wih = (const float*)d_in[1];
  const float* Whh = (const float*)d_in[2];
  const float* bih = (const float*)d_in[3];
  const float* bhh = (const float*)d_in[4];
  const float* Wfc = (const float*)d_in[5];
  const float* bfc = (const float*)d_in[6];
  float* out = (float*)d_out;
  float* hid = out + (size_t)BATCH * SEQT * NOUT;

  dim3 grid(BATCH / R);
  dim3 block(NT);
  hipLaunchKernelGGL(gru_mfma4, grid, block, 0, stream,
                     x, Wih, Whh, bih, bhh, Wfc, bfc, out, hid);
}

// Round 7
// 146.372 us; speedup vs baseline: 1.8990x; 1.2542x over previous
//
#include <hip/hip_runtime.h>
#include <math.h>

typedef __attribute__((ext_vector_type(8))) short short8;
typedef __attribute__((ext_vector_type(4))) float f32x4;

namespace {
constexpr int BATCH = 4096;
constexpr int SEQT  = 256;
constexpr int INSZ  = 24;
constexpr int H     = 40;
constexpr int NOUT  = 24;
constexpr int R     = 16;    // batch rows per block, grid = 256 (1 block/CU)
constexpr int NT    = 256;   // 4 waves: 0-2 gate (u-ranges), 3 FC + x staging

__device__ __forceinline__ unsigned short f2bf(float f) {
  unsigned int u = __float_as_uint(f);
  return (unsigned short)((u + 0x7FFFu + ((u >> 16) & 1u)) >> 16);  // RNE
}
__device__ __forceinline__ float4 ld4(const float* p) {
  return *reinterpret_cast<const float4*>(p);
}
// Native-rate transcendentals: v_exp_f32 (2^x) + v_rcp_f32, ~1 ulp each.
// Plain `1.0f/(...)` would emit the IEEE div_scale/div_fmas/div_fixup sequence
// (~10-12 instrs + ~50cy latency) since the harness compiles without fast-math;
// 12 divs/step on gate waves was the R4/R6 issue-bound plateau.
__device__ __forceinline__ float sigm(float v) {
  return __builtin_amdgcn_rcpf(1.0f + __builtin_amdgcn_exp2f(v * -1.442695041f));
}
__device__ __forceinline__ float tanh_fast(float v) {
  return fmaf(2.0f,
              __builtin_amdgcn_rcpf(1.0f + __builtin_amdgcn_exp2f(v * -2.885390082f)),
              -1.0f);
}
}  // namespace

// Raw barrier: only drain LDS ops (h/x ds_writes must be visible to readers).
// Global prefetch loads + output stores stay IN FLIGHT across the barrier.
#define BAR()                                              \
  asm volatile("s_waitcnt lgkmcnt(0)" ::: "memory");       \
  __builtin_amdgcn_s_barrier();                            \
  __builtin_amdgcn_sched_barrier(0);

// A-operand layout (bf16): Abuf row = batch row (16), k = [x(0..23) | h(24..63)],
// swizzle idx^=(row&7)<<3. Gate wave w (0..2): zone tiles r,z,nx,nh for u = w*16+lm
// (u<40). Lane (lq,lm) owns D rows lq*4+0..3 of unit u for ALL 4 zones -> in-lane
// gate math, fp32 h state in registers, one raw barrier per step.
__global__ __launch_bounds__(NT) void gru_mfma4(
    const float* __restrict__ x, const float* __restrict__ Wih,
    const float* __restrict__ Whh, const float* __restrict__ bih,
    const float* __restrict__ bhh, const float* __restrict__ Wfc,
    const float* __restrict__ bfc, float* __restrict__ out,
    float* __restrict__ hid) {
  __shared__ __align__(16) unsigned short Abuf[2 * 1024];

  const int tid = threadIdx.x;
  const int l   = tid & 63;
  const int w   = tid >> 6;
  const int lm  = l & 15;
  const int lq  = l >> 4;
  const int gb0 = blockIdx.x * R;

  reinterpret_cast<uint4*>(Abuf)[tid] = make_uint4(0, 0, 0, 0);  // zero both buffers

  const int aBase0 = ((lm * 64 + lq * 8)      ^ ((lm & 7) << 3));
  const int aBase1 = ((lm * 64 + lq * 8 + 32) ^ ((lm & 7) << 3));

  // ---------------- gate role (waves 0..2) ----------------
  short8 B[4][2];
  float bias[4] = {0, 0, 0, 0};
  float hold[4] = {0, 0, 0, 0};
  int aw[4] = {0, 0, 0, 0};
  int u = 0;
  bool gvalid = false;
  if (w < 3) {
    u = w * 16 + lm;
    gvalid = (u < H);
#pragma unroll
    for (int z = 0; z < 4; ++z) {
#pragma unroll
      for (int kt = 0; kt < 2; ++kt) {
        short8 b;
#pragma unroll
        for (int j = 0; j < 8; ++j) {
          const int k = kt * 32 + lq * 8 + j;
          float v = 0.0f;
          if (gvalid) {
            if (z == 0)      v = (k < 24) ? Wih[u * 24 + k]          : Whh[u * 40 + (k - 24)];
            else if (z == 1) v = (k < 24) ? Wih[(40 + u) * 24 + k]   : Whh[(40 + u) * 40 + (k - 24)];
            else if (z == 2) v = (k < 24) ? Wih[(80 + u) * 24 + k]   : 0.0f;
            else             v = (k < 24) ? 0.0f                     : Whh[(80 + u) * 40 + (k - 24)];
          }
          b[j] = (short)f2bf(v);
        }
        B[z][kt] = b;
      }
    }
    if (gvalid) {
      bias[0] = bih[u] + bhh[u];
      bias[1] = bih[40 + u] + bhh[40 + u];
      bias[2] = bih[80 + u];           // n input bias
      bias[3] = bhh[80 + u];           // n hidden bias (scaled by r)
    }
#pragma unroll
    for (int i = 0; i < 4; ++i)
      aw[i] = (((lq * 4 + i) * 64 + 24 + u) ^ (((lq * 4 + i) & 7) << 3));
  }

  // ---------------- FC + x role (wave 3) ----------------
  short8 F[2][2];
  float biasF[2] = {0, 0};
  float* orow[4] = {nullptr, nullptr, nullptr, nullptr};
  const float* xp0 = nullptr;
  const float* xp1 = nullptr;
  int xw0 = 0, xw1 = 0;
  bool x1v = false;
  float4 xA0 = make_float4(0,0,0,0), xA1 = make_float4(0,0,0,0);
  float4 xB0 = make_float4(0,0,0,0), xB1 = make_float4(0,0,0,0);
  if (w == 3) {
#pragma unroll
    for (int f = 0; f < 2; ++f) {
      const int o = f * 16 + lm;
#pragma unroll
      for (int kt = 0; kt < 2; ++kt) {
        short8 b;
#pragma unroll
        for (int j = 0; j < 8; ++j) {
          const int k = kt * 32 + lq * 8 + j;
          const float v = (o < NOUT && k >= 24) ? Wfc[o * H + (k - 24)] : 0.0f;
          b[j] = (short)f2bf(v);
        }
        F[f][kt] = b;
      }
      biasF[f] = (o < NOUT) ? bfc[o] : 0.0f;
    }
#pragma unroll
    for (int i = 0; i < 4; ++i)
      orow[i] = out + ((size_t)(gb0 + lq * 4 + i) * SEQT) * NOUT;

    // x staging: 96 float4 chunks (16 rows x 6), items l and 64+l (l<32)
    const int i0 = l, i1 = 64 + l;
    const int xr0 = i0 / 6, xc0 = (i0 - xr0 * 6) * 4;
    const int xr1 = i1 / 6, xc1 = (i1 - xr1 * 6) * 4;
    x1v = (l < 32);
    xp0 = x + ((size_t)(gb0 + xr0) * SEQT) * INSZ + xc0;
    if (x1v) xp1 = x + ((size_t)(gb0 + xr1) * SEQT) * INSZ + xc1;
    xw0 = ((xr0 * 64 + xc0) ^ ((xr0 & 7) << 3));
    xw1 = ((xr1 * 64 + xc1) ^ ((xr1 & 7) << 3));
  }

  __syncthreads();  // Abuf zeroed

  if (w == 3) {  // stage x(0) into buf0; prefetch x(1), x(2) into regs
    const float4 v0 = ld4(xp0);
    *reinterpret_cast<uint2*>(&Abuf[xw0]) = make_uint2(
        (unsigned)f2bf(v0.x) | ((unsigned)f2bf(v0.y) << 16),
        (unsigned)f2bf(v0.z) | ((unsigned)f2bf(v0.w) << 16));
    if (x1v) {
      const float4 v1 = ld4(xp1);
      *reinterpret_cast<uint2*>(&Abuf[xw1]) = make_uint2(
          (unsigned)f2bf(v1.x) | ((unsigned)f2bf(v1.y) << 16),
          (unsigned)f2bf(v1.z) | ((unsigned)f2bf(v1.w) << 16));
    }
    xA0 = ld4(xp0 + 1 * INSZ);
    xB0 = ld4(xp0 + 2 * INSZ);
    if (x1v) { xA1 = ld4(xp1 + 1 * INSZ); xB1 = ld4(xp1 + 2 * INSZ); }
  }
  __syncthreads();  // x(0) staged

#define GATE_STEP(BO, NBO)                                                      \
  if (w < 3) {                                                                  \
    const short8 A0 = *reinterpret_cast<const short8*>(&Abuf[(BO) + aBase0]);   \
    const short8 A1 = *reinterpret_cast<const short8*>(&Abuf[(BO) + aBase1]);   \
    f32x4 ar = {bias[0], bias[0], bias[0], bias[0]};                            \
    f32x4 az = {bias[1], bias[1], bias[1], bias[1]};                            \
    f32x4 ax = {bias[2], bias[2], bias[2], bias[2]};                            \
    f32x4 ah = {bias[3], bias[3], bias[3], bias[3]};                            \
    ar = __builtin_amdgcn_mfma_f32_16x16x32_bf16(A0, B[0][0], ar, 0, 0, 0);     \
    az = __builtin_amdgcn_mfma_f32_16x16x32_bf16(A0, B[1][0], az, 0, 0, 0);     \
    ax = __builtin_amdgcn_mfma_f32_16x16x32_bf16(A0, B[2][0], ax, 0, 0, 0);     \
    ah = __builtin_amdgcn_mfma_f32_16x16x32_bf16(A0, B[3][0], ah, 0, 0, 0);     \
    ar = __builtin_amdgcn_mfma_f32_16x16x32_bf16(A1, B[0][1], ar, 0, 0, 0);     \
    az = __builtin_amdgcn_mfma_f32_16x16x32_bf16(A1, B[1][1], az, 0, 0, 0);     \
    ax = __builtin_amdgcn_mfma_f32_16x16x32_bf16(A1, B[2][1], ax, 0, 0, 0);     \
    ah = __builtin_amdgcn_mfma_f32_16x16x32_bf16(A1, B[3][1], ah, 0, 0, 0);     \
    _Pragma("unroll")                                                           \
    for (int i = 0; i < 4; ++i) {                                               \
      const float rr = sigm(ar[i]);                                             \
      const float zz = sigm(az[i]);                                             \
      const float nn = tanh_fast(fmaf(rr, ah[i], ax[i]));                       \
      const float h  = fmaf(zz, hold[i] - nn, nn);                              \
      hold[i] = h;                                                              \
      if (gvalid) Abuf[(NBO) + aw[i]] = f2bf(h);                                \
    }                                                                           \
  }

#define XSTAGE(T, NBO, XS0, XS1)                                                \
  if (w == 3) {                                                                 \
    *reinterpret_cast<uint2*>(&Abuf[(NBO) + xw0]) = make_uint2(                 \
        (unsigned)f2bf(XS0.x) | ((unsigned)f2bf(XS0.y) << 16),                  \
        (unsigned)f2bf(XS0.z) | ((unsigned)f2bf(XS0.w) << 16));                 \
    if (x1v)                                                                    \
      *reinterpret_cast<uint2*>(&Abuf[(NBO) + xw1]) = make_uint2(               \
          (unsigned)f2bf(XS1.x) | ((unsigned)f2bf(XS1.y) << 16),                \
          (unsigned)f2bf(XS1.z) | ((unsigned)f2bf(XS1.w) << 16));               \
    if ((T) + 3 < SEQT) {                                                       \
      XS0 = ld4(xp0 + (size_t)((T) + 3) * INSZ);                                \
      if (x1v) XS1 = ld4(xp1 + (size_t)((T) + 3) * INSZ);                       \
    }                                                                           \
  }

#define FC_STEP(T, NBO)                                                         \
  if (w == 3) {                                                                 \
    const short8 hA0 = *reinterpret_cast<const short8*>(&Abuf[(NBO) + aBase0]); \
    const short8 hA1 = *reinterpret_cast<const short8*>(&Abuf[(NBO) + aBase1]); \
    f32x4 f0 = {biasF[0], biasF[0], biasF[0], biasF[0]};                        \
    f32x4 f1 = {biasF[1], biasF[1], biasF[1], biasF[1]};                        \
    f0 = __builtin_amdgcn_mfma_f32_16x16x32_bf16(hA0, F[0][0], f0, 0, 0, 0);    \
    f1 = __builtin_amdgcn_mfma_f32_16x16x32_bf16(hA0, F[1][0], f1, 0, 0, 0);    \
    f0 = __builtin_amdgcn_mfma_f32_16x16x32_bf16(hA1, F[0][1], f0, 0, 0, 0);    \
    f1 = __builtin_amdgcn_mfma_f32_16x16x32_bf16(hA1, F[1][1], f1, 0, 0, 0);    \
    _Pragma("unroll")                                                           \
    for (int i = 0; i < 4; ++i) {                                               \
      orow[i][(size_t)(T) * NOUT + lm] = sigm(f0[i]);                           \
      if (lm < 8) orow[i][(size_t)(T) * NOUT + 16 + lm] = sigm(f1[i]);          \
    }                                                                           \
  }

  for (int tt = 0; tt < SEQT; tt += 2) {
    // step t = tt (even): cur buf 0, next buf 1
    GATE_STEP(0, 1024)
    XSTAGE(tt, 1024, xA0, xA1)
    BAR()
    FC_STEP(tt, 1024)
    // step t = tt+1 (odd): cur buf 1, next buf 0
    GATE_STEP(1024, 0)
    XSTAGE(tt + 1, 0, xB0, xB1)
    BAR()
    FC_STEP(tt + 1, 0)
  }

  // final hidden state from registers
  if (w < 3 && gvalid) {
#pragma unroll
    for (int i = 0; i < 4; ++i)
      hid[(size_t)(gb0 + lq * 4 + i) * H + u] = hold[i];
  }
}

extern "C" void kernel_launch(void* const* d_in, const int* in_sizes, int n_in,
                              void* d_out, int out_size, void* d_ws, size_t ws_size,
                              hipStream_t stream) {
  const float* x   = (const float*)d_in[0];
  const float* Wih = (const float*)d_in[1];
  const float* Whh = (const float*)d_in[2];
  const float* bih = (const float*)d_in[3];
  const float* bhh = (const float*)d_in[4];
  const float* Wfc = (const float*)d_in[5];
  const float* bfc = (const float*)d_in[6];
  float* out = (float*)d_out;
  float* hid = out + (size_t)BATCH * SEQT * NOUT;

  dim3 grid(BATCH / R);
  dim3 block(NT);
  hipLaunchKernelGGL(gru_mfma4, grid, block, 0, stream,
                     x, Wih, Whh, bih, bhh, Wfc, bfc, out, hid);
}